// Round 3
// baseline (4493.212 us; speedup 1.0000x reference)
//
#include <hip/hip_runtime.h>
#include <hip/hip_bf16.h>
#include <stdint.h>

#define HD 128
#define GD 64
#define OUTD 16

// ---------------------------------------------------------------- utilities
__global__ void zero_k(float* p, int n) {
  int i = blockIdx.x * 256 + threadIdx.x;
  if (i < n) p[i] = 0.f;
}

// Detect int64 vs int32 layout of edge_index: for int64 (values in [0,N),
// nonneg < 2^31) every odd int32 word is 0; for 64 random int32 indices
// that's ~impossible (p ~ (1/50000)^64).
__global__ void detect_k(const int* ei, int* flag) {
  if (threadIdx.x == 0 && blockIdx.x == 0) {
    int all0 = 1;
    for (int k = 1; k < 128; k += 2) all0 &= (ei[k] == 0);
    *flag = all0;
  }
}

// Normalize edge_index and batch to int32 in ws (branch-free downstream).
__global__ void convert_idx_k(const int* ei, const int* bt, int* idx, int* b32,
                              int E, int N, const int* flag) {
  int i = blockIdx.x * 256 + threadIdx.x;
  int is64 = *flag;
  if (i < 2 * E) {
    int v = is64 ? ei[2 * i] : ei[i];
    idx[i] = (v < 0) ? 0 : (v >= N ? N - 1 : v);
  }
  if (i < N) {
    int v = is64 ? bt[2 * i] : bt[i];
    b32[i] = (v < 0) ? 0 : (v >= GD ? GD - 1 : v);
  }
}

// w[e] = |nan_to_num(edge_attr[e])| ; deg[col[e]] += w
__global__ void edge_prep_k(const int* __restrict__ idx, const float* __restrict__ ea,
                            float* __restrict__ wbuf, float* __restrict__ deg, int E) {
  int e = blockIdx.x * 256 + threadIdx.x;
  if (e >= E) return;
  float a = ea[e];
  float w = isnan(a) ? 0.f : fabsf(a);
  wbuf[e] = w;
  int col = idx[E + e];
  unsafeAtomicAdd(&deg[col], w);
}

__global__ void dinv_k(float* dinv, int N) {
  int i = blockIdx.x * 256 + threadIdx.x;
  if (i < N) dinv[i] = rsqrtf(dinv[i] + 1.0f);
}

// norm[e] = dinv[row]*w[e]*dinv[col]   (in place on wbuf)
__global__ void norm_k(const int* __restrict__ idx, const float* __restrict__ dinv,
                       float* __restrict__ wbuf, int E) {
  int e = blockIdx.x * 256 + threadIdx.x;
  if (e >= E) return;
  wbuf[e] = dinv[idx[e]] * wbuf[e] * dinv[idx[E + e]];
}

// h0 = concat(nan_to_num(x), isnan(x))  [N,128] fp32
__global__ void build_h0_k(const float* __restrict__ x, float* __restrict__ A, int N) {
  int i = blockIdx.x * 256 + threadIdx.x;
  if (i >= N * HD) return;
  int n = i >> 7, f = i & 127;
  float v;
  if (f < 64) { float u = x[n * 64 + f];      v = isnan(u) ? 0.f : u; }
  else        { float u = x[n * 64 + f - 64]; v = isnan(u) ? 1.f : 0.f; }
  A[i] = v;
}

// C[N,128] = H[N,128] @ W[128,128]   (all fp32)
// 64-row tile / block of 128 threads, 8x8 register blocking, K split in 2.
__global__ __launch_bounds__(128)
void gemm_k(const float* __restrict__ Hm, const float* __restrict__ W,
            float* __restrict__ C, int N) {
  __shared__ float sht[64][64];    // [k_local][r], 16 KB
  __shared__ float sw[64][128];    // [k_local][c], 32 KB
  const int t = threadIdx.x;
  const int r0 = blockIdx.x * 64;
  const int rbase = (t >> 4) * 8;  // 0..56
  const int cbase = (t & 15) * 8;  // 0..120

  float acc[8][8];
#pragma unroll
  for (int r = 0; r < 8; ++r)
#pragma unroll
    for (int c = 0; c < 8; ++c) acc[r][c] = 0.f;

  for (int kb = 0; kb < 2; ++kb) {
    // load H chunk: 64 rows x 64 k-cols -> 1024 float4, 8 per thread
#pragma unroll
    for (int k = 0; k < 8; ++k) {
      int q = t + k * 128;
      int r = q >> 4;             // 0..63
      int c4 = (q & 15) << 2;     // 0..60
      float4 hv = make_float4(0.f, 0.f, 0.f, 0.f);
      if (r0 + r < N) hv = *(const float4*)(Hm + (size_t)(r0 + r) * HD + kb * 64 + c4);
      sht[c4 + 0][r] = hv.x; sht[c4 + 1][r] = hv.y;
      sht[c4 + 2][r] = hv.z; sht[c4 + 3][r] = hv.w;
    }
    // load W chunk: 64 k-rows x 128 cols -> 2048 float4, 16 per thread
#pragma unroll
    for (int k = 0; k < 16; ++k) {
      int q = t + k * 128;
      int kr = q >> 5;            // 0..63
      int c4 = (q & 31) << 2;     // 0..124
      *(float4*)&sw[kr][c4] = *(const float4*)(W + (size_t)(kb * 64 + kr) * HD + c4);
    }
    __syncthreads();
#pragma unroll 4
    for (int i = 0; i < 64; ++i) {
      float hreg[8], wreg[8];
      *(float4*)&hreg[0] = *(const float4*)&sht[i][rbase];
      *(float4*)&hreg[4] = *(const float4*)&sht[i][rbase + 4];
      *(float4*)&wreg[0] = *(const float4*)&sw[i][cbase];
      *(float4*)&wreg[4] = *(const float4*)&sw[i][cbase + 4];
#pragma unroll
      for (int r = 0; r < 8; ++r)
#pragma unroll
        for (int c = 0; c < 8; ++c) acc[r][c] += hreg[r] * wreg[c];
    }
    __syncthreads();
  }
#pragma unroll
  for (int r = 0; r < 8; ++r) {
    int row = r0 + rbase + r;
    if (row < N) {
      *(float4*)(C + (size_t)row * HD + cbase)     = *(float4*)&acc[r][0];
      *(float4*)(C + (size_t)row * HD + cbase + 4) = *(float4*)&acc[r][4];
    }
  }
}

// agg init: A = dinv[n]^2 * B + bias   (self-loop + bias)
__global__ void selfinit_k(const float* __restrict__ B, const float* __restrict__ dinv,
                           const float* __restrict__ bias, float* __restrict__ A, int N) {
  int i = blockIdx.x * 256 + threadIdx.x;
  if (i >= N * HD) return;
  int n = i >> 7, j = i & 127;
  float d = dinv[n];
  A[i] = d * d * B[i] + bias[j];
}

// edge scatter: A[col] += norm[e] * B[row]   (32 lanes/edge, float4 each)
__global__ __launch_bounds__(256)
void scatter_k(const int* __restrict__ idx, const float* __restrict__ norm,
               const float* __restrict__ B, float* __restrict__ A, int E) {
  int tid = blockIdx.x * 256 + threadIdx.x;
  int e = tid >> 5;
  if (e >= E) return;
  int f4 = (tid & 31) << 2;
  int row = idx[e];
  int col = idx[E + e];
  float nv = norm[e];
  float4 hv = *(const float4*)(B + (size_t)row * HD + f4);
  float* dst = A + (size_t)col * HD + f4;
  unsafeAtomicAdd(dst + 0, nv * hv.x);
  unsafeAtomicAdd(dst + 1, nv * hv.y);
  unsafeAtomicAdd(dst + 2, nv * hv.z);
  unsafeAtomicAdd(dst + 3, nv * hv.w);
}

__global__ void bnrelu_k(float* __restrict__ A, const float* __restrict__ gamma,
                         const float* __restrict__ beta, const float* __restrict__ mean,
                         const float* __restrict__ var, int N) {
  int i = blockIdx.x * 256 + threadIdx.x;
  if (i >= N * HD) return;
  int j = i & 127;
  float s = gamma[j] * rsqrtf(var[j] + 1e-5f);
  float v = (A[i] - mean[j]) * s + beta[j];
  A[i] = v > 0.f ? v : 0.f;
}

// segment starts via binary search on sorted batch (65 entries)
__global__ void start_k(const int* __restrict__ b32, int* __restrict__ start, int N) {
  int b = threadIdx.x;
  if (b > GD) return;
  int lo = 0, hi = N;
  while (lo < hi) {
    int mid = (lo + hi) >> 1;
    if (b32[mid] < b) lo = mid + 1; else hi = mid;
  }
  start[b] = lo;
}

// mean pool: g[b][j] = mean over segment
__global__ __launch_bounds__(128)
void pool_k(const float* __restrict__ A, const int* __restrict__ start,
            float* __restrict__ g) {
  int b = blockIdx.x, j = threadIdx.x;
  int s = start[b], e = start[b + 1];
  float a0 = 0.f, a1 = 0.f;
  int n = s;
  for (; n + 1 < e; n += 2) {
    a0 += A[(size_t)n * HD + j];
    a1 += A[(size_t)(n + 1) * HD + j];
  }
  if (n < e) a0 += A[(size_t)n * HD + j];
  int cnt = e - s;
  g[b * HD + j] = (a0 + a1) / (float)(cnt > 0 ? cnt : 1);
}

// out = gelu(g@mW1+mb1) @ mW2 + mb2, one block per graph; out is fp32
__global__ __launch_bounds__(128)
void mlp_k(const float* __restrict__ g, const float* __restrict__ mW1,
           const float* __restrict__ mb1, const float* __restrict__ mW2,
           const float* __restrict__ mb2, float* __restrict__ out) {
  __shared__ float sg[128];
  __shared__ float st[128];
  int b = blockIdx.x, j = threadIdx.x;
  sg[j] = g[b * HD + j];
  __syncthreads();
  float s = mb1[j];
#pragma unroll 4
  for (int i = 0; i < 128; ++i) s += sg[i] * mW1[i * 128 + j];
  float ge = 0.5f * s * (1.0f + erff(s * 0.70710678118654752f));
  st[j] = ge;
  __syncthreads();
  if (j < OUTD) {
    float o = mb2[j];
#pragma unroll 4
    for (int k = 0; k < 128; ++k) o += st[k] * mW2[k * OUTD + j];
    out[b * OUTD + j] = o;   // fp32 output, per reference output dtype
  }
}

// ---------------------------------------------------------------- launch
extern "C" void kernel_launch(void* const* d_in, const int* in_sizes, int n_in,
                              void* d_out, int out_size, void* d_ws, size_t ws_size,
                              hipStream_t stream) {
  const float* x   = (const float*)d_in[0];
  const int* ei    = (const int*)d_in[1];
  const float* ea  = (const float*)d_in[2];
  const int* bt    = (const int*)d_in[3];
  const float* W0  = (const float*)d_in[4];
  const float* b0  = (const float*)d_in[5];
  const float* W1  = (const float*)d_in[6];
  const float* b1  = (const float*)d_in[7];
  const float* W2  = (const float*)d_in[8];
  const float* b2  = (const float*)d_in[9];
  const float* bng = (const float*)d_in[10];
  const float* bnb = (const float*)d_in[11];
  const float* bnm = (const float*)d_in[12];
  const float* bnv = (const float*)d_in[13];
  const float* mW1 = (const float*)d_in[14];
  const float* mb1 = (const float*)d_in[15];
  const float* mW2 = (const float*)d_in[16];
  const float* mb2 = (const float*)d_in[17];
  float* out = (float*)d_out;

  const int N = in_sizes[0] / 64;      // 50000
  const int E = in_sizes[2];           // 800000

  char* ws = (char*)d_ws;
  size_t NB = (size_t)N * HD * 4;
  float* A    = (float*)(ws);                       // h / agg
  float* B    = (float*)(ws + NB);                  // h@W
  float* nrm  = (float*)(ws + 2 * NB);              // E floats
  float* dinv = (float*)(ws + 2 * NB + (size_t)E * 4);
  float* gbuf = (float*)((char*)dinv + (size_t)N * 4);          // 64*128
  int*   strt = (int*)((char*)gbuf + GD * HD * 4);              // 65 ints
  int*   flag = (int*)((char*)strt + 68 * 4);
  int*   idx  = (int*)((char*)flag + 64);                       // 2E ints
  int*   b32  = (int*)((char*)idx + (size_t)2 * E * 4);         // N ints

  const int NH = N * HD;
  dim3 blk(256);
  int gNH = (NH + 255) / 256;
  int gE  = (E + 255) / 256;
  int gN  = (N + 255) / 256;
  int gCv = (2 * E + 255) / 256;

  detect_k<<<1, 64, 0, stream>>>(ei, flag);
  convert_idx_k<<<gCv, blk, 0, stream>>>(ei, bt, idx, b32, E, N, flag);
  zero_k<<<gN, blk, 0, stream>>>(dinv, N);
  edge_prep_k<<<gE, blk, 0, stream>>>(idx, ea, nrm, dinv, E);
  dinv_k<<<gN, blk, 0, stream>>>(dinv, N);
  norm_k<<<gE, blk, 0, stream>>>(idx, dinv, nrm, E);
  build_h0_k<<<gNH, blk, 0, stream>>>(x, A, N);

  int gGemm = (N + 63) / 64;
  int gScat = (E * 32 + 255) / 256;

  // layer 0
  gemm_k<<<gGemm, 128, 0, stream>>>(A, W0, B, N);
  selfinit_k<<<gNH, blk, 0, stream>>>(B, dinv, b0, A, N);
  scatter_k<<<gScat, blk, 0, stream>>>(idx, nrm, B, A, E);
  bnrelu_k<<<gNH, blk, 0, stream>>>(A, bng, bnb, bnm, bnv, N);
  // layer 1
  gemm_k<<<gGemm, 128, 0, stream>>>(A, W1, B, N);
  selfinit_k<<<gNH, blk, 0, stream>>>(B, dinv, b1, A, N);
  scatter_k<<<gScat, blk, 0, stream>>>(idx, nrm, B, A, E);
  bnrelu_k<<<gNH, blk, 0, stream>>>(A, bng, bnb, bnm, bnv, N);
  // layer 2 (no bn/relu)
  gemm_k<<<gGemm, 128, 0, stream>>>(A, W2, B, N);
  selfinit_k<<<gNH, blk, 0, stream>>>(B, dinv, b2, A, N);
  scatter_k<<<gScat, blk, 0, stream>>>(idx, nrm, B, A, E);

  start_k<<<1, 128, 0, stream>>>(b32, strt, N);
  pool_k<<<GD, 128, 0, stream>>>(A, strt, gbuf);
  mlp_k<<<GD, 128, 0, stream>>>(gbuf, mW1, mb1, mW2, mb2, out);
}

// Round 4
// 682.997 us; speedup vs baseline: 6.5787x; 6.5787x over previous
//
#include <hip/hip_runtime.h>
#include <hip/hip_bf16.h>
#include <stdint.h>

#define HD 128
#define GD 64
#define OUTD 16

// ---------------------------------------------------------------- utilities
__global__ void zero_f_k(float* p, int n) {
  int i = blockIdx.x * 256 + threadIdx.x;
  if (i < n) p[i] = 0.f;
}
__global__ void zero_i_k(int* p, int n) {
  int i = blockIdx.x * 256 + threadIdx.x;
  if (i < n) p[i] = 0;
}

// Detect int64 vs int32 layout of edge_index: for int64 (values in [0,N))
// every odd int32 word is 0; for 64 random int32 indices that's ~impossible.
__global__ void detect_k(const int* ei, int* flag) {
  if (threadIdx.x == 0 && blockIdx.x == 0) {
    int all0 = 1;
    for (int k = 1; k < 128; k += 2) all0 &= (ei[k] == 0);
    *flag = all0;
  }
}

// Normalize edge_index and batch to int32 in ws.
__global__ void convert_idx_k(const int* ei, const int* bt, int* idx, int* b32,
                              int E, int N, const int* flag) {
  int i = blockIdx.x * 256 + threadIdx.x;
  int is64 = *flag;
  if (i < 2 * E) {
    int v = is64 ? ei[2 * i] : ei[i];
    idx[i] = (v < 0) ? 0 : (v >= N ? N - 1 : v);
  }
  if (i < N) {
    int v = is64 ? bt[2 * i] : bt[i];
    b32[i] = (v < 0) ? 0 : (v >= GD ? GD - 1 : v);
  }
}

// w[e] = |nan_to_num(edge_attr[e])| ; deg[col] += w ; cnt[col] += 1
__global__ void edge_prep_k(const int* __restrict__ idx, const float* __restrict__ ea,
                            float* __restrict__ wbuf, float* __restrict__ deg,
                            int* __restrict__ cnt, int E) {
  int e = blockIdx.x * 256 + threadIdx.x;
  if (e >= E) return;
  float a = ea[e];
  float w = isnan(a) ? 0.f : fabsf(a);
  wbuf[e] = w;
  int col = idx[E + e];
  unsafeAtomicAdd(&deg[col], w);
  atomicAdd(&cnt[col], 1);
}

__global__ void dinv_k(float* dinv, int N) {
  int i = blockIdx.x * 256 + threadIdx.x;
  if (i < N) dinv[i] = rsqrtf(dinv[i] + 1.0f);
}

// ---- 3-step exclusive scan of cnt[0..N) -> offs, cursor
__global__ void scan1_k(const int* __restrict__ cnt, int* __restrict__ offs,
                        int* __restrict__ bsum, int Np) {
  __shared__ int s[1024];
  int i = blockIdx.x * 1024 + threadIdx.x;
  int v = (i < Np) ? cnt[i] : 0;
  s[threadIdx.x] = v;
  __syncthreads();
  for (int off = 1; off < 1024; off <<= 1) {
    int t = (threadIdx.x >= off) ? s[threadIdx.x - off] : 0;
    __syncthreads();
    s[threadIdx.x] += t;
    __syncthreads();
  }
  if (i < Np) offs[i] = s[threadIdx.x] - v;   // block-local exclusive
  if (threadIdx.x == 1023) bsum[blockIdx.x] = s[1023];
}
__global__ void scan2_k(int* bsum, int nb) {
  if (threadIdx.x == 0 && blockIdx.x == 0) {
    int sum = 0;
    for (int i = 0; i < nb; ++i) { int v = bsum[i]; bsum[i] = sum; sum += v; }
  }
}
__global__ void scan3_k(int* __restrict__ offs, const int* __restrict__ bsum,
                        int* __restrict__ cursor, int Np, int E) {
  int i = blockIdx.x * 256 + threadIdx.x;
  if (i < Np) {
    int o = offs[i] + bsum[i >> 10];
    offs[i] = o;
    cursor[i] = o;
  }
  if (i == 0) offs[Np] = E;
}

// fill CSC: srow/snorm sorted by destination (col)
__global__ void fill_k(const int* __restrict__ idx, const float* __restrict__ wbuf,
                       const float* __restrict__ dinv, int* __restrict__ cursor,
                       int* __restrict__ srow, float* __restrict__ snorm, int E) {
  int e = blockIdx.x * 256 + threadIdx.x;
  if (e >= E) return;
  int row = idx[e], col = idx[E + e];
  float nv = dinv[row] * wbuf[e] * dinv[col];
  int p = atomicAdd(&cursor[col], 1);
  srow[p] = row;
  snorm[p] = nv;
}

// h0 = concat(nan_to_num(x), isnan(x))  [N,128] fp32
__global__ void build_h0_k(const float* __restrict__ x, float* __restrict__ A, int N) {
  int i = blockIdx.x * 256 + threadIdx.x;
  if (i >= N * HD) return;
  int n = i >> 7, f = i & 127;
  float v;
  if (f < 64) { float u = x[n * 64 + f];      v = isnan(u) ? 0.f : u; }
  else        { float u = x[n * 64 + f - 64]; v = isnan(u) ? 1.f : 0.f; }
  A[i] = v;
}

// C[N,128] = H[N,128] @ W[128,128]   (all fp32)
__global__ __launch_bounds__(128)
void gemm_k(const float* __restrict__ Hm, const float* __restrict__ W,
            float* __restrict__ C, int N) {
  __shared__ float sht[64][64];
  __shared__ float sw[64][128];
  const int t = threadIdx.x;
  const int r0 = blockIdx.x * 64;
  const int rbase = (t >> 4) * 8;
  const int cbase = (t & 15) * 8;

  float acc[8][8];
#pragma unroll
  for (int r = 0; r < 8; ++r)
#pragma unroll
    for (int c = 0; c < 8; ++c) acc[r][c] = 0.f;

  for (int kb = 0; kb < 2; ++kb) {
#pragma unroll
    for (int k = 0; k < 8; ++k) {
      int q = t + k * 128;
      int r = q >> 4;
      int c4 = (q & 15) << 2;
      float4 hv = make_float4(0.f, 0.f, 0.f, 0.f);
      if (r0 + r < N) hv = *(const float4*)(Hm + (size_t)(r0 + r) * HD + kb * 64 + c4);
      sht[c4 + 0][r] = hv.x; sht[c4 + 1][r] = hv.y;
      sht[c4 + 2][r] = hv.z; sht[c4 + 3][r] = hv.w;
    }
#pragma unroll
    for (int k = 0; k < 16; ++k) {
      int q = t + k * 128;
      int kr = q >> 5;
      int c4 = (q & 31) << 2;
      *(float4*)&sw[kr][c4] = *(const float4*)(W + (size_t)(kb * 64 + kr) * HD + c4);
    }
    __syncthreads();
#pragma unroll 4
    for (int i = 0; i < 64; ++i) {
      float hreg[8], wreg[8];
      *(float4*)&hreg[0] = *(const float4*)&sht[i][rbase];
      *(float4*)&hreg[4] = *(const float4*)&sht[i][rbase + 4];
      *(float4*)&wreg[0] = *(const float4*)&sw[i][cbase];
      *(float4*)&wreg[4] = *(const float4*)&sw[i][cbase + 4];
#pragma unroll
      for (int r = 0; r < 8; ++r)
#pragma unroll
        for (int c = 0; c < 8; ++c) acc[r][c] += hreg[r] * wreg[c];
    }
    __syncthreads();
  }
#pragma unroll
  for (int r = 0; r < 8; ++r) {
    int row = r0 + rbase + r;
    if (row < N) {
      *(float4*)(C + (size_t)row * HD + cbase)     = *(float4*)&acc[r][0];
      *(float4*)(C + (size_t)row * HD + cbase + 4) = *(float4*)&acc[r][4];
    }
  }
}

// Fused: A[n] = BN?ReLU( dinv[n]^2*B[n] + bias + sum_in norm*B[row] )
// 32 lanes per node, float4 per lane.
__global__ __launch_bounds__(256)
void aggregate_k(const int* __restrict__ offs, const int* __restrict__ srow,
                 const float* __restrict__ snorm, const float* __restrict__ B,
                 const float* __restrict__ dinv, const float* __restrict__ bias,
                 const float* __restrict__ gamma, const float* __restrict__ beta,
                 const float* __restrict__ mean, const float* __restrict__ var,
                 int do_bn, float* __restrict__ A, int N) {
  int tid = blockIdx.x * 256 + threadIdx.x;
  int n = tid >> 5;
  if (n >= N) return;
  int f4 = (tid & 31) << 2;
  float d = dinv[n];
  float4 bv = *(const float4*)(B + (size_t)n * HD + f4);
  float ax = d * d * bv.x + bias[f4 + 0];
  float ay = d * d * bv.y + bias[f4 + 1];
  float az = d * d * bv.z + bias[f4 + 2];
  float aw = d * d * bv.w + bias[f4 + 3];

  int p = offs[n], pe = offs[n + 1];
  for (; p + 1 < pe; p += 2) {
    int r0 = srow[p], r1 = srow[p + 1];
    float w0 = snorm[p], w1 = snorm[p + 1];
    float4 h0 = *(const float4*)(B + (size_t)r0 * HD + f4);
    float4 h1 = *(const float4*)(B + (size_t)r1 * HD + f4);
    ax += w0 * h0.x + w1 * h1.x;
    ay += w0 * h0.y + w1 * h1.y;
    az += w0 * h0.z + w1 * h1.z;
    aw += w0 * h0.w + w1 * h1.w;
  }
  if (p < pe) {
    int r0 = srow[p];
    float w0 = snorm[p];
    float4 h0 = *(const float4*)(B + (size_t)r0 * HD + f4);
    ax += w0 * h0.x; ay += w0 * h0.y; az += w0 * h0.z; aw += w0 * h0.w;
  }
  if (do_bn) {
    float s0 = gamma[f4 + 0] * rsqrtf(var[f4 + 0] + 1e-5f);
    float s1 = gamma[f4 + 1] * rsqrtf(var[f4 + 1] + 1e-5f);
    float s2 = gamma[f4 + 2] * rsqrtf(var[f4 + 2] + 1e-5f);
    float s3 = gamma[f4 + 3] * rsqrtf(var[f4 + 3] + 1e-5f);
    ax = (ax - mean[f4 + 0]) * s0 + beta[f4 + 0];
    ay = (ay - mean[f4 + 1]) * s1 + beta[f4 + 1];
    az = (az - mean[f4 + 2]) * s2 + beta[f4 + 2];
    aw = (aw - mean[f4 + 3]) * s3 + beta[f4 + 3];
    ax = ax > 0.f ? ax : 0.f;
    ay = ay > 0.f ? ay : 0.f;
    az = az > 0.f ? az : 0.f;
    aw = aw > 0.f ? aw : 0.f;
  }
  float4 r = make_float4(ax, ay, az, aw);
  *(float4*)(A + (size_t)n * HD + f4) = r;
}

// segment starts via binary search on sorted batch
__global__ void start_k(const int* __restrict__ b32, int* __restrict__ start, int N) {
  int b = threadIdx.x;
  if (b > GD) return;
  int lo = 0, hi = N;
  while (lo < hi) {
    int mid = (lo + hi) >> 1;
    if (b32[mid] < b) lo = mid + 1; else hi = mid;
  }
  start[b] = lo;
}

__global__ __launch_bounds__(128)
void pool_k(const float* __restrict__ A, const int* __restrict__ start,
            float* __restrict__ g) {
  int b = blockIdx.x, j = threadIdx.x;
  int s = start[b], e = start[b + 1];
  float a0 = 0.f, a1 = 0.f;
  int n = s;
  for (; n + 1 < e; n += 2) {
    a0 += A[(size_t)n * HD + j];
    a1 += A[(size_t)(n + 1) * HD + j];
  }
  if (n < e) a0 += A[(size_t)n * HD + j];
  int cnt = e - s;
  g[b * HD + j] = (a0 + a1) / (float)(cnt > 0 ? cnt : 1);
}

__global__ __launch_bounds__(128)
void mlp_k(const float* __restrict__ g, const float* __restrict__ mW1,
           const float* __restrict__ mb1, const float* __restrict__ mW2,
           const float* __restrict__ mb2, float* __restrict__ out) {
  __shared__ float sg[128];
  __shared__ float st[128];
  int b = blockIdx.x, j = threadIdx.x;
  sg[j] = g[b * HD + j];
  __syncthreads();
  float s = mb1[j];
#pragma unroll 4
  for (int i = 0; i < 128; ++i) s += sg[i] * mW1[i * 128 + j];
  float ge = 0.5f * s * (1.0f + erff(s * 0.70710678118654752f));
  st[j] = ge;
  __syncthreads();
  if (j < OUTD) {
    float o = mb2[j];
#pragma unroll 4
    for (int k = 0; k < 128; ++k) o += st[k] * mW2[k * OUTD + j];
    out[b * OUTD + j] = o;
  }
}

// ---------------------------------------------------------------- launch
extern "C" void kernel_launch(void* const* d_in, const int* in_sizes, int n_in,
                              void* d_out, int out_size, void* d_ws, size_t ws_size,
                              hipStream_t stream) {
  const float* x   = (const float*)d_in[0];
  const int* ei    = (const int*)d_in[1];
  const float* ea  = (const float*)d_in[2];
  const int* bt    = (const int*)d_in[3];
  const float* W0  = (const float*)d_in[4];
  const float* b0  = (const float*)d_in[5];
  const float* W1  = (const float*)d_in[6];
  const float* b1  = (const float*)d_in[7];
  const float* W2  = (const float*)d_in[8];
  const float* b2  = (const float*)d_in[9];
  const float* bng = (const float*)d_in[10];
  const float* bnb = (const float*)d_in[11];
  const float* bnm = (const float*)d_in[12];
  const float* bnv = (const float*)d_in[13];
  const float* mW1 = (const float*)d_in[14];
  const float* mb1 = (const float*)d_in[15];
  const float* mW2 = (const float*)d_in[16];
  const float* mb2 = (const float*)d_in[17];
  float* out = (float*)d_out;

  const int N = in_sizes[0] / 64;      // 50000
  const int E = in_sizes[2];           // 800000

  char* ws = (char*)d_ws;
  size_t NB = (size_t)N * HD * 4;
  float* A     = (float*)(ws);                      // [N,128]
  float* B     = (float*)(ws + NB);                 // [N,128]
  char*  q     = ws + 2 * NB;
  float* wbuf  = (float*)q;            q += (size_t)E * 4;   // edge |w|
  float* snorm = (float*)q;            q += (size_t)E * 4;   // CSC norm
  int*   srow  = (int*)q;              q += (size_t)E * 4;   // CSC row
  int*   idx   = (int*)q;              q += (size_t)2 * E * 4;
  float* dinv  = (float*)q;            q += (size_t)N * 4;
  int*   cnt   = (int*)q;              q += (size_t)N * 4;   // also cursor
  int*   offs  = (int*)q;              q += (size_t)(N + 2) * 4;
  int*   b32   = (int*)q;              q += (size_t)N * 4;
  int*   bsum  = (int*)q;              q += 64 * 4;
  float* gbuf  = (float*)q;            q += GD * HD * 4;
  int*   strt  = (int*)q;              q += 68 * 4;
  int*   flag  = (int*)q;

  const int NH = N * HD;
  dim3 blk(256);
  int gNH = (NH + 255) / 256;
  int gE  = (E + 255) / 256;
  int gN  = (N + 255) / 256;
  int gCv = (2 * E + 255) / 256;
  int nb1024 = (N + 1023) / 1024;

  detect_k<<<1, 64, 0, stream>>>(ei, flag);
  convert_idx_k<<<gCv, blk, 0, stream>>>(ei, bt, idx, b32, E, N, flag);
  zero_f_k<<<gN, blk, 0, stream>>>(dinv, N);
  zero_i_k<<<gN, blk, 0, stream>>>(cnt, N);
  edge_prep_k<<<gE, blk, 0, stream>>>(idx, ea, wbuf, dinv, cnt, E);
  dinv_k<<<gN, blk, 0, stream>>>(dinv, N);
  scan1_k<<<nb1024, 1024, 0, stream>>>(cnt, offs, bsum, N);
  scan2_k<<<1, 64, 0, stream>>>(bsum, nb1024);
  scan3_k<<<gN, blk, 0, stream>>>(offs, bsum, cnt /*cursor*/, N, E);
  fill_k<<<gE, blk, 0, stream>>>(idx, wbuf, dinv, cnt, srow, snorm, E);
  build_h0_k<<<gNH, blk, 0, stream>>>(x, A, N);

  int gGemm = (N + 63) / 64;
  int gAgg  = (N * 32 + 255) / 256;

  // layer 0
  gemm_k<<<gGemm, 128, 0, stream>>>(A, W0, B, N);
  aggregate_k<<<gAgg, blk, 0, stream>>>(offs, srow, snorm, B, dinv, b0,
                                        bng, bnb, bnm, bnv, 1, A, N);
  // layer 1
  gemm_k<<<gGemm, 128, 0, stream>>>(A, W1, B, N);
  aggregate_k<<<gAgg, blk, 0, stream>>>(offs, srow, snorm, B, dinv, b1,
                                        bng, bnb, bnm, bnv, 1, A, N);
  // layer 2 (no bn/relu)
  gemm_k<<<gGemm, 128, 0, stream>>>(A, W2, B, N);
  aggregate_k<<<gAgg, blk, 0, stream>>>(offs, srow, snorm, B, dinv, b2,
                                        bng, bnb, bnm, bnv, 0, A, N);

  start_k<<<1, 128, 0, stream>>>(b32, strt, N);
  pool_k<<<GD, 128, 0, stream>>>(A, strt, gbuf);
  mlp_k<<<GD, 128, 0, stream>>>(gbuf, mW1, mb1, mW2, mb2, out);
}

// Round 5
// 596.940 us; speedup vs baseline: 7.5271x; 1.1442x over previous
//
#include <hip/hip_runtime.h>
#include <hip/hip_bf16.h>
#include <stdint.h>

#define HD 128
#define GD 64
#define OUTD 16

// ---------------------------------------------------------------- utilities
__global__ void zero_f_k(float* p, int n) {
  int i = blockIdx.x * 256 + threadIdx.x;
  if (i < n) p[i] = 0.f;
}
__global__ void zero_i_k(int* p, int n) {
  int i = blockIdx.x * 256 + threadIdx.x;
  if (i < n) p[i] = 0;
}

// Detect int64 vs int32 layout of edge_index: for int64 (values in [0,N))
// every odd int32 word is 0; for 64 random int32 indices that's ~impossible.
__global__ void detect_k(const int* ei, int* flag) {
  if (threadIdx.x == 0 && blockIdx.x == 0) {
    int all0 = 1;
    for (int k = 1; k < 128; k += 2) all0 &= (ei[k] == 0);
    *flag = all0;
  }
}

// Normalize edge_index and batch to int32 in ws.
__global__ void convert_idx_k(const int* ei, const int* bt, int* idx, int* b32,
                              int E, int N, const int* flag) {
  int i = blockIdx.x * 256 + threadIdx.x;
  int is64 = *flag;
  if (i < 2 * E) {
    int v = is64 ? ei[2 * i] : ei[i];
    idx[i] = (v < 0) ? 0 : (v >= N ? N - 1 : v);
  }
  if (i < N) {
    int v = is64 ? bt[2 * i] : bt[i];
    b32[i] = (v < 0) ? 0 : (v >= GD ? GD - 1 : v);
  }
}

// w[e] = |nan_to_num(edge_attr[e])| ; deg[col] += w ; cnt[col] += 1
__global__ void edge_prep_k(const int* __restrict__ idx, const float* __restrict__ ea,
                            float* __restrict__ wbuf, float* __restrict__ deg,
                            int* __restrict__ cnt, int E) {
  int e = blockIdx.x * 256 + threadIdx.x;
  if (e >= E) return;
  float a = ea[e];
  float w = isnan(a) ? 0.f : fabsf(a);
  wbuf[e] = w;
  int col = idx[E + e];
  unsafeAtomicAdd(&deg[col], w);
  atomicAdd(&cnt[col], 1);
}

__global__ void dinv_k(float* dinv, int N) {
  int i = blockIdx.x * 256 + threadIdx.x;
  if (i < N) dinv[i] = rsqrtf(dinv[i] + 1.0f);
}

// ---- 3-step exclusive scan of cnt[0..N) -> offs, cursor
__global__ void scan1_k(const int* __restrict__ cnt, int* __restrict__ offs,
                        int* __restrict__ bsum, int Np) {
  __shared__ int s[1024];
  int i = blockIdx.x * 1024 + threadIdx.x;
  int v = (i < Np) ? cnt[i] : 0;
  s[threadIdx.x] = v;
  __syncthreads();
  for (int off = 1; off < 1024; off <<= 1) {
    int t = (threadIdx.x >= off) ? s[threadIdx.x - off] : 0;
    __syncthreads();
    s[threadIdx.x] += t;
    __syncthreads();
  }
  if (i < Np) offs[i] = s[threadIdx.x] - v;   // block-local exclusive
  if (threadIdx.x == 1023) bsum[blockIdx.x] = s[1023];
}
__global__ void scan2_k(int* bsum, int nb) {
  if (threadIdx.x == 0 && blockIdx.x == 0) {
    int sum = 0;
    for (int i = 0; i < nb; ++i) { int v = bsum[i]; bsum[i] = sum; sum += v; }
  }
}
__global__ void scan3_k(int* __restrict__ offs, const int* __restrict__ bsum,
                        int* __restrict__ cursor, int Np, int E) {
  int i = blockIdx.x * 256 + threadIdx.x;
  if (i < Np) {
    int o = offs[i] + bsum[i >> 10];
    offs[i] = o;
    cursor[i] = o;
  }
  if (i == 0) offs[Np] = E;
}

// fill CSC: srow/snorm sorted by destination (col)
__global__ void fill_k(const int* __restrict__ idx, const float* __restrict__ wbuf,
                       const float* __restrict__ dinv, int* __restrict__ cursor,
                       int* __restrict__ srow, float* __restrict__ snorm, int E) {
  int e = blockIdx.x * 256 + threadIdx.x;
  if (e >= E) return;
  int row = idx[e], col = idx[E + e];
  float nv = dinv[row] * wbuf[e] * dinv[col];
  int p = atomicAdd(&cursor[col], 1);
  srow[p] = row;
  snorm[p] = nv;
}

// h0 = concat(nan_to_num(x), isnan(x))  [N,128] fp32
__global__ void build_h0_k(const float* __restrict__ x, float* __restrict__ A, int N) {
  int i = blockIdx.x * 256 + threadIdx.x;
  if (i >= N * HD) return;
  int n = i >> 7, f = i & 127;
  float v;
  if (f < 64) { float u = x[n * 64 + f];      v = isnan(u) ? 0.f : u; }
  else        { float u = x[n * 64 + f - 64]; v = isnan(u) ? 1.f : 0.f; }
  A[i] = v;
}

// C[N,128] = H[N,128] @ W[128,128]   (all fp32)
__global__ __launch_bounds__(128)
void gemm_k(const float* __restrict__ Hm, const float* __restrict__ W,
            float* __restrict__ C, int N) {
  __shared__ float sht[64][64];
  __shared__ float sw[64][128];
  const int t = threadIdx.x;
  const int r0 = blockIdx.x * 64;
  const int rbase = (t >> 4) * 8;
  const int cbase = (t & 15) * 8;

  float acc[8][8];
#pragma unroll
  for (int r = 0; r < 8; ++r)
#pragma unroll
    for (int c = 0; c < 8; ++c) acc[r][c] = 0.f;

  for (int kb = 0; kb < 2; ++kb) {
#pragma unroll
    for (int k = 0; k < 8; ++k) {
      int q = t + k * 128;
      int r = q >> 4;
      int c4 = (q & 15) << 2;
      float4 hv = make_float4(0.f, 0.f, 0.f, 0.f);
      if (r0 + r < N) hv = *(const float4*)(Hm + (size_t)(r0 + r) * HD + kb * 64 + c4);
      sht[c4 + 0][r] = hv.x; sht[c4 + 1][r] = hv.y;
      sht[c4 + 2][r] = hv.z; sht[c4 + 3][r] = hv.w;
    }
#pragma unroll
    for (int k = 0; k < 16; ++k) {
      int q = t + k * 128;
      int kr = q >> 5;
      int c4 = (q & 31) << 2;
      *(float4*)&sw[kr][c4] = *(const float4*)(W + (size_t)(kb * 64 + kr) * HD + c4);
    }
    __syncthreads();
#pragma unroll 4
    for (int i = 0; i < 64; ++i) {
      float hreg[8], wreg[8];
      *(float4*)&hreg[0] = *(const float4*)&sht[i][rbase];
      *(float4*)&hreg[4] = *(const float4*)&sht[i][rbase + 4];
      *(float4*)&wreg[0] = *(const float4*)&sw[i][cbase];
      *(float4*)&wreg[4] = *(const float4*)&sw[i][cbase + 4];
#pragma unroll
      for (int r = 0; r < 8; ++r)
#pragma unroll
        for (int c = 0; c < 8; ++c) acc[r][c] += hreg[r] * wreg[c];
    }
    __syncthreads();
  }
#pragma unroll
  for (int r = 0; r < 8; ++r) {
    int row = r0 + rbase + r;
    if (row < N) {
      *(float4*)(C + (size_t)row * HD + cbase)     = *(float4*)&acc[r][0];
      *(float4*)(C + (size_t)row * HD + cbase + 4) = *(float4*)&acc[r][4];
    }
  }
}

// Fused: A[n] = BN?ReLU( dinv[n]^2*B[n] + bias + sum_in norm*B[row] )
// 32 lanes per node, float4 per lane.
__global__ __launch_bounds__(256)
void aggregate_k(const int* __restrict__ offs, const int* __restrict__ srow,
                 const float* __restrict__ snorm, const float* __restrict__ B,
                 const float* __restrict__ dinv, const float* __restrict__ bias,
                 const float* __restrict__ gamma, const float* __restrict__ beta,
                 const float* __restrict__ mean, const float* __restrict__ var,
                 int do_bn, float* __restrict__ A, int N) {
  int tid = blockIdx.x * 256 + threadIdx.x;
  int n = tid >> 5;
  if (n >= N) return;
  int f4 = (tid & 31) << 2;
  float d = dinv[n];
  float4 bv = *(const float4*)(B + (size_t)n * HD + f4);
  float ax = d * d * bv.x + bias[f4 + 0];
  float ay = d * d * bv.y + bias[f4 + 1];
  float az = d * d * bv.z + bias[f4 + 2];
  float aw = d * d * bv.w + bias[f4 + 3];

  int p = offs[n], pe = offs[n + 1];
  for (; p + 1 < pe; p += 2) {
    int r0 = srow[p], r1 = srow[p + 1];
    float w0 = snorm[p], w1 = snorm[p + 1];
    float4 h0 = *(const float4*)(B + (size_t)r0 * HD + f4);
    float4 h1 = *(const float4*)(B + (size_t)r1 * HD + f4);
    ax += w0 * h0.x + w1 * h1.x;
    ay += w0 * h0.y + w1 * h1.y;
    az += w0 * h0.z + w1 * h1.z;
    aw += w0 * h0.w + w1 * h1.w;
  }
  if (p < pe) {
    int r0 = srow[p];
    float w0 = snorm[p];
    float4 h0 = *(const float4*)(B + (size_t)r0 * HD + f4);
    ax += w0 * h0.x; ay += w0 * h0.y; az += w0 * h0.z; aw += w0 * h0.w;
  }
  if (do_bn) {
    float s0 = gamma[f4 + 0] * rsqrtf(var[f4 + 0] + 1e-5f);
    float s1 = gamma[f4 + 1] * rsqrtf(var[f4 + 1] + 1e-5f);
    float s2 = gamma[f4 + 2] * rsqrtf(var[f4 + 2] + 1e-5f);
    float s3 = gamma[f4 + 3] * rsqrtf(var[f4 + 3] + 1e-5f);
    ax = (ax - mean[f4 + 0]) * s0 + beta[f4 + 0];
    ay = (ay - mean[f4 + 1]) * s1 + beta[f4 + 1];
    az = (az - mean[f4 + 2]) * s2 + beta[f4 + 2];
    aw = (aw - mean[f4 + 3]) * s3 + beta[f4 + 3];
    ax = ax > 0.f ? ax : 0.f;
    ay = ay > 0.f ? ay : 0.f;
    az = az > 0.f ? az : 0.f;
    aw = aw > 0.f ? aw : 0.f;
  }
  float4 r = make_float4(ax, ay, az, aw);
  *(float4*)(A + (size_t)n * HD + f4) = r;
}

// segment starts via binary search on sorted batch
__global__ void start_k(const int* __restrict__ b32, int* __restrict__ start, int N) {
  int b = threadIdx.x;
  if (b > GD) return;
  int lo = 0, hi = N;
  while (lo < hi) {
    int mid = (lo + hi) >> 1;
    if (b32[mid] < b) lo = mid + 1; else hi = mid;
  }
  start[b] = lo;
}

// two-stage mean pool, stage 1: chunked partial sums + one atomic per (thread)
// grid: (NCHUNK, GD), block 128
__global__ __launch_bounds__(128)
void pool1_k(const float* __restrict__ A, const int* __restrict__ start,
             float* __restrict__ sums) {
  int b = blockIdx.y;
  int s = start[b], e = start[b + 1];
  int len = e - s;
  if (len <= 0) return;
  int nch = gridDim.x;
  int ch = (len + nch - 1) / nch;
  int lo = s + blockIdx.x * ch;
  int hi = lo + ch; if (hi > e) hi = e;
  if (lo >= hi) return;
  int j = threadIdx.x;
  float a0 = 0.f, a1 = 0.f, a2 = 0.f, a3 = 0.f;
  int n = lo;
  for (; n + 3 < hi; n += 4) {
    a0 += A[(size_t)(n + 0) * HD + j];
    a1 += A[(size_t)(n + 1) * HD + j];
    a2 += A[(size_t)(n + 2) * HD + j];
    a3 += A[(size_t)(n + 3) * HD + j];
  }
  for (; n < hi; ++n) a0 += A[(size_t)n * HD + j];
  unsafeAtomicAdd(&sums[b * HD + j], (a0 + a1) + (a2 + a3));
}

// out = gelu((sums/cnt)@mW1+mb1) @ mW2 + mb2, one block per graph; fp32 out
__global__ __launch_bounds__(128)
void mlp_k(const float* __restrict__ sums, const int* __restrict__ start,
           const float* __restrict__ mW1, const float* __restrict__ mb1,
           const float* __restrict__ mW2, const float* __restrict__ mb2,
           float* __restrict__ out) {
  __shared__ float sg[128];
  __shared__ float st[128];
  int b = blockIdx.x, j = threadIdx.x;
  int cnt = start[b + 1] - start[b];
  float inv = 1.0f / (float)(cnt > 0 ? cnt : 1);
  sg[j] = sums[b * HD + j] * inv;
  __syncthreads();
  float s = mb1[j];
#pragma unroll 4
  for (int i = 0; i < 128; ++i) s += sg[i] * mW1[i * 128 + j];
  float ge = 0.5f * s * (1.0f + erff(s * 0.70710678118654752f));
  st[j] = ge;
  __syncthreads();
  if (j < OUTD) {
    float o = mb2[j];
#pragma unroll 4
    for (int k = 0; k < 128; ++k) o += st[k] * mW2[k * OUTD + j];
    out[b * OUTD + j] = o;
  }
}

// ---------------------------------------------------------------- launch
extern "C" void kernel_launch(void* const* d_in, const int* in_sizes, int n_in,
                              void* d_out, int out_size, void* d_ws, size_t ws_size,
                              hipStream_t stream) {
  const float* x   = (const float*)d_in[0];
  const int* ei    = (const int*)d_in[1];
  const float* ea  = (const float*)d_in[2];
  const int* bt    = (const int*)d_in[3];
  const float* W0  = (const float*)d_in[4];
  const float* b0  = (const float*)d_in[5];
  const float* W1  = (const float*)d_in[6];
  const float* b1  = (const float*)d_in[7];
  const float* W2  = (const float*)d_in[8];
  const float* b2  = (const float*)d_in[9];
  const float* bng = (const float*)d_in[10];
  const float* bnb = (const float*)d_in[11];
  const float* bnm = (const float*)d_in[12];
  const float* bnv = (const float*)d_in[13];
  const float* mW1 = (const float*)d_in[14];
  const float* mb1 = (const float*)d_in[15];
  const float* mW2 = (const float*)d_in[16];
  const float* mb2 = (const float*)d_in[17];
  float* out = (float*)d_out;

  const int N = in_sizes[0] / 64;      // 50000
  const int E = in_sizes[2];           // 800000

  char* ws = (char*)d_ws;
  size_t NB = (size_t)N * HD * 4;
  float* A     = (float*)(ws);                      // [N,128]
  float* B     = (float*)(ws + NB);                 // [N,128]
  char*  q     = ws + 2 * NB;
  float* wbuf  = (float*)q;            q += (size_t)E * 4;   // edge |w|
  float* snorm = (float*)q;            q += (size_t)E * 4;   // CSC norm
  int*   srow  = (int*)q;              q += (size_t)E * 4;   // CSC row
  int*   idx   = (int*)q;              q += (size_t)2 * E * 4;
  float* dinv  = (float*)q;            q += (size_t)N * 4;
  int*   cnt   = (int*)q;              q += (size_t)N * 4;   // also cursor
  int*   offs  = (int*)q;              q += (size_t)(N + 2) * 4;
  int*   b32   = (int*)q;              q += (size_t)N * 4;
  int*   bsum  = (int*)q;              q += 64 * 4;
  float* sums  = (float*)q;            q += GD * HD * 4;
  int*   strt  = (int*)q;              q += 68 * 4;
  int*   flag  = (int*)q;

  const int NH = N * HD;
  dim3 blk(256);
  int gNH = (NH + 255) / 256;
  int gE  = (E + 255) / 256;
  int gN  = (N + 255) / 256;
  int gCv = (2 * E + 255) / 256;
  int nb1024 = (N + 1023) / 1024;

  detect_k<<<1, 64, 0, stream>>>(ei, flag);
  convert_idx_k<<<gCv, blk, 0, stream>>>(ei, bt, idx, b32, E, N, flag);
  zero_f_k<<<gN, blk, 0, stream>>>(dinv, N);
  zero_i_k<<<gN, blk, 0, stream>>>(cnt, N);
  zero_f_k<<<(GD * HD + 255) / 256, blk, 0, stream>>>(sums, GD * HD);
  edge_prep_k<<<gE, blk, 0, stream>>>(idx, ea, wbuf, dinv, cnt, E);
  dinv_k<<<gN, blk, 0, stream>>>(dinv, N);
  scan1_k<<<nb1024, 1024, 0, stream>>>(cnt, offs, bsum, N);
  scan2_k<<<1, 64, 0, stream>>>(bsum, nb1024);
  scan3_k<<<gN, blk, 0, stream>>>(offs, bsum, cnt /*cursor*/, N, E);
  fill_k<<<gE, blk, 0, stream>>>(idx, wbuf, dinv, cnt, srow, snorm, E);
  build_h0_k<<<gNH, blk, 0, stream>>>(x, A, N);

  int gGemm = (N + 63) / 64;
  int gAgg  = (N * 32 + 255) / 256;

  // layer 0
  gemm_k<<<gGemm, 128, 0, stream>>>(A, W0, B, N);
  aggregate_k<<<gAgg, blk, 0, stream>>>(offs, srow, snorm, B, dinv, b0,
                                        bng, bnb, bnm, bnv, 1, A, N);
  // layer 1
  gemm_k<<<gGemm, 128, 0, stream>>>(A, W1, B, N);
  aggregate_k<<<gAgg, blk, 0, stream>>>(offs, srow, snorm, B, dinv, b1,
                                        bng, bnb, bnm, bnv, 1, A, N);
  // layer 2 (no bn/relu)
  gemm_k<<<gGemm, 128, 0, stream>>>(A, W2, B, N);
  aggregate_k<<<gAgg, blk, 0, stream>>>(offs, srow, snorm, B, dinv, b2,
                                        bng, bnb, bnm, bnv, 0, A, N);

  start_k<<<1, 128, 0, stream>>>(b32, strt, N);
  dim3 pgrid(16, GD);
  pool1_k<<<pgrid, 128, 0, stream>>>(A, strt, sums);
  mlp_k<<<GD, 128, 0, stream>>>(sums, strt, mW1, mb1, mW2, mb2, out);
}

// Round 6
// 559.098 us; speedup vs baseline: 8.0365x; 1.0677x over previous
//
#include <hip/hip_runtime.h>
#include <hip/hip_bf16.h>
#include <stdint.h>

#define HD 128
#define GD 64
#define OUTD 16

// ---------------------------------------------------------------- utilities
__global__ void zero_f_k(float* p, int n) {
  int i = blockIdx.x * 256 + threadIdx.x;
  if (i < n) p[i] = 0.f;
}
__global__ void zero_i_k(int* p, int n) {
  int i = blockIdx.x * 256 + threadIdx.x;
  if (i < n) p[i] = 0;
}

// Detect int64 vs int32 layout of edge_index.
__global__ void detect_k(const int* ei, int* flag) {
  if (threadIdx.x == 0 && blockIdx.x == 0) {
    int all0 = 1;
    for (int k = 1; k < 128; k += 2) all0 &= (ei[k] == 0);
    *flag = all0;
  }
}

// Normalize edge_index and batch to int32 in ws.
__global__ void convert_idx_k(const int* ei, const int* bt, int* idx, int* b32,
                              int E, int N, const int* flag) {
  int i = blockIdx.x * 256 + threadIdx.x;
  int is64 = *flag;
  if (i < 2 * E) {
    int v = is64 ? ei[2 * i] : ei[i];
    idx[i] = (v < 0) ? 0 : (v >= N ? N - 1 : v);
  }
  if (i < N) {
    int v = is64 ? bt[2 * i] : bt[i];
    b32[i] = (v < 0) ? 0 : (v >= GD ? GD - 1 : v);
  }
}

// privatized in-degree count: replica k = blockIdx & 7
__global__ void count_k(const int* __restrict__ idx, int* __restrict__ cnt8,
                        int E, int N) {
  int e = blockIdx.x * 256 + threadIdx.x;
  if (e >= E) return;
  int k = blockIdx.x & 7;
  int col = idx[E + e];
  atomicAdd(&cnt8[k * N + col], 1);
}

__global__ void reduce_cnt_k(const int* __restrict__ cnt8, int* __restrict__ cnt, int N) {
  int n = blockIdx.x * 256 + threadIdx.x;
  if (n >= N) return;
  int s = 0;
#pragma unroll
  for (int k = 0; k < 8; ++k) s += cnt8[k * N + n];
  cnt[n] = s;
}

// ---- 3-step exclusive scan of cnt[0..N) -> offs
__global__ void scan1_k(const int* __restrict__ cnt, int* __restrict__ offs,
                        int* __restrict__ bsum, int Np) {
  __shared__ int s[1024];
  int i = blockIdx.x * 1024 + threadIdx.x;
  int v = (i < Np) ? cnt[i] : 0;
  s[threadIdx.x] = v;
  __syncthreads();
  for (int off = 1; off < 1024; off <<= 1) {
    int t = (threadIdx.x >= off) ? s[threadIdx.x - off] : 0;
    __syncthreads();
    s[threadIdx.x] += t;
    __syncthreads();
  }
  if (i < Np) offs[i] = s[threadIdx.x] - v;
  if (threadIdx.x == 1023) bsum[blockIdx.x] = s[1023];
}
__global__ void scan2_k(int* bsum, int nb) {
  if (threadIdx.x == 0 && blockIdx.x == 0) {
    int sum = 0;
    for (int i = 0; i < nb; ++i) { int v = bsum[i]; bsum[i] = sum; sum += v; }
  }
}
__global__ void scan3_k(int* __restrict__ offs, const int* __restrict__ bsum,
                        int Np, int E) {
  int i = blockIdx.x * 256 + threadIdx.x;
  if (i < Np) offs[i] = offs[i] + bsum[i >> 10];
  if (i == 0) offs[Np] = E;
}

// per-replica cursors: curs8[k][n] = offs[n] + sum_{k'<k} cnt8[k'][n]
__global__ void curs8_k(const int* __restrict__ offs, const int* __restrict__ cnt8,
                        int* __restrict__ curs8, int N) {
  int n = blockIdx.x * 256 + threadIdx.x;
  if (n >= N) return;
  int run = offs[n];
#pragma unroll
  for (int k = 0; k < 8; ++k) { curs8[k * N + n] = run; run += cnt8[k * N + n]; }
}

// fill CSC (sorted by destination col): srow + sorted |w|
__global__ void fill_k(const int* __restrict__ idx, const float* __restrict__ ea,
                       int* __restrict__ curs8, int* __restrict__ srow,
                       float* __restrict__ sws, int E, int N) {
  int e = blockIdx.x * 256 + threadIdx.x;
  if (e >= E) return;
  int k = blockIdx.x & 7;
  int row = idx[e], col = idx[E + e];
  float a = ea[e];
  float w = isnan(a) ? 0.f : fabsf(a);
  int p = atomicAdd(&curs8[k * N + col], 1);
  srow[p] = row;
  sws[p] = w;
}

// dinv[n] = rsqrt(sum of in-weights + 1)
__global__ void deg_k(const int* __restrict__ offs, const float* __restrict__ sws,
                      float* __restrict__ dinv, int N) {
  int n = blockIdx.x * 256 + threadIdx.x;
  if (n >= N) return;
  int p = offs[n], pe = offs[n + 1];
  float s = 0.f;
  for (; p < pe; ++p) s += sws[p];
  dinv[n] = rsqrtf(s + 1.0f);
}

// snorm[p] = dinv[row]*w*dinv[col]
__global__ void normcsc_k(const int* __restrict__ offs, const int* __restrict__ srow,
                          const float* __restrict__ sws, const float* __restrict__ dinv,
                          float* __restrict__ snorm, int N) {
  int n = blockIdx.x * 256 + threadIdx.x;
  if (n >= N) return;
  float dc = dinv[n];
  int p = offs[n], pe = offs[n + 1];
  for (; p < pe; ++p) snorm[p] = dinv[srow[p]] * sws[p] * dc;
}

// h0 = concat(nan_to_num(x), isnan(x))  [N,128] fp32
__global__ void build_h0_k(const float* __restrict__ x, float* __restrict__ A, int N) {
  int i = blockIdx.x * 256 + threadIdx.x;
  if (i >= N * HD) return;
  int n = i >> 7, f = i & 127;
  float v;
  if (f < 64) { float u = x[n * 64 + f];      v = isnan(u) ? 0.f : u; }
  else        { float u = x[n * 64 + f - 64]; v = isnan(u) ? 1.f : 0.f; }
  A[i] = v;
}

// C[N,128] = H[N,128] @ W[128,128]   (all fp32)
__global__ __launch_bounds__(128)
void gemm_k(const float* __restrict__ Hm, const float* __restrict__ W,
            float* __restrict__ C, int N) {
  __shared__ float sht[64][64];
  __shared__ float sw[64][128];
  const int t = threadIdx.x;
  const int r0 = blockIdx.x * 64;
  const int rbase = (t >> 4) * 8;
  const int cbase = (t & 15) * 8;

  float acc[8][8];
#pragma unroll
  for (int r = 0; r < 8; ++r)
#pragma unroll
    for (int c = 0; c < 8; ++c) acc[r][c] = 0.f;

  for (int kb = 0; kb < 2; ++kb) {
#pragma unroll
    for (int k = 0; k < 8; ++k) {
      int q = t + k * 128;
      int r = q >> 4;
      int c4 = (q & 15) << 2;
      float4 hv = make_float4(0.f, 0.f, 0.f, 0.f);
      if (r0 + r < N) hv = *(const float4*)(Hm + (size_t)(r0 + r) * HD + kb * 64 + c4);
      sht[c4 + 0][r] = hv.x; sht[c4 + 1][r] = hv.y;
      sht[c4 + 2][r] = hv.z; sht[c4 + 3][r] = hv.w;
    }
#pragma unroll
    for (int k = 0; k < 16; ++k) {
      int q = t + k * 128;
      int kr = q >> 5;
      int c4 = (q & 31) << 2;
      *(float4*)&sw[kr][c4] = *(const float4*)(W + (size_t)(kb * 64 + kr) * HD + c4);
    }
    __syncthreads();
#pragma unroll 4
    for (int i = 0; i < 64; ++i) {
      float hreg[8], wreg[8];
      *(float4*)&hreg[0] = *(const float4*)&sht[i][rbase];
      *(float4*)&hreg[4] = *(const float4*)&sht[i][rbase + 4];
      *(float4*)&wreg[0] = *(const float4*)&sw[i][cbase];
      *(float4*)&wreg[4] = *(const float4*)&sw[i][cbase + 4];
#pragma unroll
      for (int r = 0; r < 8; ++r)
#pragma unroll
        for (int c = 0; c < 8; ++c) acc[r][c] += hreg[r] * wreg[c];
    }
    __syncthreads();
  }
#pragma unroll
  for (int r = 0; r < 8; ++r) {
    int row = r0 + rbase + r;
    if (row < N) {
      *(float4*)(C + (size_t)row * HD + cbase)     = *(float4*)&acc[r][0];
      *(float4*)(C + (size_t)row * HD + cbase + 4) = *(float4*)&acc[r][4];
    }
  }
}

// Fused: A[n] = BN?ReLU( dinv[n]^2*B[n] + bias + sum_in norm*B[row] )
__global__ __launch_bounds__(256)
void aggregate_k(const int* __restrict__ offs, const int* __restrict__ srow,
                 const float* __restrict__ snorm, const float* __restrict__ B,
                 const float* __restrict__ dinv, const float* __restrict__ bias,
                 const float* __restrict__ gamma, const float* __restrict__ beta,
                 const float* __restrict__ mean, const float* __restrict__ var,
                 int do_bn, float* __restrict__ A, int N) {
  int tid = blockIdx.x * 256 + threadIdx.x;
  int n = tid >> 5;
  if (n >= N) return;
  int f4 = (tid & 31) << 2;
  float d = dinv[n];
  float4 bv = *(const float4*)(B + (size_t)n * HD + f4);
  float ax = d * d * bv.x + bias[f4 + 0];
  float ay = d * d * bv.y + bias[f4 + 1];
  float az = d * d * bv.z + bias[f4 + 2];
  float aw = d * d * bv.w + bias[f4 + 3];

  int p = offs[n], pe = offs[n + 1];
  for (; p + 1 < pe; p += 2) {
    int r0 = srow[p], r1 = srow[p + 1];
    float w0 = snorm[p], w1 = snorm[p + 1];
    float4 h0 = *(const float4*)(B + (size_t)r0 * HD + f4);
    float4 h1 = *(const float4*)(B + (size_t)r1 * HD + f4);
    ax += w0 * h0.x + w1 * h1.x;
    ay += w0 * h0.y + w1 * h1.y;
    az += w0 * h0.z + w1 * h1.z;
    aw += w0 * h0.w + w1 * h1.w;
  }
  if (p < pe) {
    int r0 = srow[p];
    float w0 = snorm[p];
    float4 h0 = *(const float4*)(B + (size_t)r0 * HD + f4);
    ax += w0 * h0.x; ay += w0 * h0.y; az += w0 * h0.z; aw += w0 * h0.w;
  }
  if (do_bn) {
    float s0 = gamma[f4 + 0] * rsqrtf(var[f4 + 0] + 1e-5f);
    float s1 = gamma[f4 + 1] * rsqrtf(var[f4 + 1] + 1e-5f);
    float s2 = gamma[f4 + 2] * rsqrtf(var[f4 + 2] + 1e-5f);
    float s3 = gamma[f4 + 3] * rsqrtf(var[f4 + 3] + 1e-5f);
    ax = (ax - mean[f4 + 0]) * s0 + beta[f4 + 0];
    ay = (ay - mean[f4 + 1]) * s1 + beta[f4 + 1];
    az = (az - mean[f4 + 2]) * s2 + beta[f4 + 2];
    aw = (aw - mean[f4 + 3]) * s3 + beta[f4 + 3];
    ax = ax > 0.f ? ax : 0.f;
    ay = ay > 0.f ? ay : 0.f;
    az = az > 0.f ? az : 0.f;
    aw = aw > 0.f ? aw : 0.f;
  }
  float4 r = make_float4(ax, ay, az, aw);
  *(float4*)(A + (size_t)n * HD + f4) = r;
}

// segment starts via binary search on sorted batch
__global__ void start_k(const int* __restrict__ b32, int* __restrict__ start, int N) {
  int b = threadIdx.x;
  if (b > GD) return;
  int lo = 0, hi = N;
  while (lo < hi) {
    int mid = (lo + hi) >> 1;
    if (b32[mid] < b) lo = mid + 1; else hi = mid;
  }
  start[b] = lo;
}

// two-stage mean pool, stage 1
__global__ __launch_bounds__(128)
void pool1_k(const float* __restrict__ A, const int* __restrict__ start,
             float* __restrict__ sums) {
  int b = blockIdx.y;
  int s = start[b], e = start[b + 1];
  int len = e - s;
  if (len <= 0) return;
  int nch = gridDim.x;
  int ch = (len + nch - 1) / nch;
  int lo = s + blockIdx.x * ch;
  int hi = lo + ch; if (hi > e) hi = e;
  if (lo >= hi) return;
  int j = threadIdx.x;
  float a0 = 0.f, a1 = 0.f, a2 = 0.f, a3 = 0.f;
  int n = lo;
  for (; n + 3 < hi; n += 4) {
    a0 += A[(size_t)(n + 0) * HD + j];
    a1 += A[(size_t)(n + 1) * HD + j];
    a2 += A[(size_t)(n + 2) * HD + j];
    a3 += A[(size_t)(n + 3) * HD + j];
  }
  for (; n < hi; ++n) a0 += A[(size_t)n * HD + j];
  unsafeAtomicAdd(&sums[b * HD + j], (a0 + a1) + (a2 + a3));
}

// out = gelu((sums/cnt)@mW1+mb1) @ mW2 + mb2
__global__ __launch_bounds__(128)
void mlp_k(const float* __restrict__ sums, const int* __restrict__ start,
           const float* __restrict__ mW1, const float* __restrict__ mb1,
           const float* __restrict__ mW2, const float* __restrict__ mb2,
           float* __restrict__ out) {
  __shared__ float sg[128];
  __shared__ float st[128];
  int b = blockIdx.x, j = threadIdx.x;
  int cnt = start[b + 1] - start[b];
  float inv = 1.0f / (float)(cnt > 0 ? cnt : 1);
  sg[j] = sums[b * HD + j] * inv;
  __syncthreads();
  float s = mb1[j];
#pragma unroll 4
  for (int i = 0; i < 128; ++i) s += sg[i] * mW1[i * 128 + j];
  float ge = 0.5f * s * (1.0f + erff(s * 0.70710678118654752f));
  st[j] = ge;
  __syncthreads();
  if (j < OUTD) {
    float o = mb2[j];
#pragma unroll 4
    for (int k = 0; k < 128; ++k) o += st[k] * mW2[k * OUTD + j];
    out[b * OUTD + j] = o;
  }
}

// ---------------------------------------------------------------- launch
extern "C" void kernel_launch(void* const* d_in, const int* in_sizes, int n_in,
                              void* d_out, int out_size, void* d_ws, size_t ws_size,
                              hipStream_t stream) {
  const float* x   = (const float*)d_in[0];
  const int* ei    = (const int*)d_in[1];
  const float* ea  = (const float*)d_in[2];
  const int* bt    = (const int*)d_in[3];
  const float* W0  = (const float*)d_in[4];
  const float* b0  = (const float*)d_in[5];
  const float* W1  = (const float*)d_in[6];
  const float* b1  = (const float*)d_in[7];
  const float* W2  = (const float*)d_in[8];
  const float* b2  = (const float*)d_in[9];
  const float* bng = (const float*)d_in[10];
  const float* bnb = (const float*)d_in[11];
  const float* bnm = (const float*)d_in[12];
  const float* bnv = (const float*)d_in[13];
  const float* mW1 = (const float*)d_in[14];
  const float* mb1 = (const float*)d_in[15];
  const float* mW2 = (const float*)d_in[16];
  const float* mb2 = (const float*)d_in[17];
  float* out = (float*)d_out;

  const int N = in_sizes[0] / 64;      // 50000
  const int E = in_sizes[2];           // 800000

  char* ws = (char*)d_ws;
  size_t NB = (size_t)N * HD * 4;
  float* A     = (float*)(ws);                      // [N,128]
  float* B     = (float*)(ws + NB);                 // [N,128]
  char*  q     = ws + 2 * NB;
  float* snorm = (float*)q;            q += (size_t)E * 4;
  int*   srow  = (int*)q;              q += (size_t)E * 4;
  float* sws   = (float*)q;            q += (size_t)E * 4;   // sorted |w|
  int*   idx   = (int*)q;              q += (size_t)2 * E * 4;
  float* dinv  = (float*)q;            q += (size_t)N * 4;
  int*   cnt8  = (int*)q;              q += (size_t)8 * N * 4;
  int*   curs8 = (int*)q;              q += (size_t)8 * N * 4;
  int*   cnt   = (int*)q;              q += (size_t)N * 4;
  int*   offs  = (int*)q;              q += (size_t)(N + 2) * 4;
  int*   b32   = (int*)q;              q += (size_t)N * 4;
  int*   bsum  = (int*)q;              q += 64 * 4;
  float* sums  = (float*)q;            q += GD * HD * 4;
  int*   strt  = (int*)q;              q += 68 * 4;
  int*   flag  = (int*)q;

  const int NH = N * HD;
  dim3 blk(256);
  int gNH = (NH + 255) / 256;
  int gE  = (E + 255) / 256;
  int gN  = (N + 255) / 256;
  int gCv = (2 * E + 255) / 256;
  int nb1024 = (N + 1023) / 1024;

  detect_k<<<1, 64, 0, stream>>>(ei, flag);
  convert_idx_k<<<gCv, blk, 0, stream>>>(ei, bt, idx, b32, E, N, flag);
  zero_i_k<<<(8 * N + 255) / 256, blk, 0, stream>>>(cnt8, 8 * N);
  zero_f_k<<<(GD * HD + 255) / 256, blk, 0, stream>>>(sums, GD * HD);
  count_k<<<gE, blk, 0, stream>>>(idx, cnt8, E, N);
  reduce_cnt_k<<<gN, blk, 0, stream>>>(cnt8, cnt, N);
  scan1_k<<<nb1024, 1024, 0, stream>>>(cnt, offs, bsum, N);
  scan2_k<<<1, 64, 0, stream>>>(bsum, nb1024);
  scan3_k<<<gN, blk, 0, stream>>>(offs, bsum, N, E);
  curs8_k<<<gN, blk, 0, stream>>>(offs, cnt8, curs8, N);
  fill_k<<<gE, blk, 0, stream>>>(idx, ea, curs8, srow, sws, E, N);
  deg_k<<<gN, blk, 0, stream>>>(offs, sws, dinv, N);
  normcsc_k<<<gN, blk, 0, stream>>>(offs, srow, sws, dinv, snorm, N);
  build_h0_k<<<gNH, blk, 0, stream>>>(x, A, N);

  int gGemm = (N + 63) / 64;
  int gAgg  = (N * 32 + 255) / 256;

  // layer 0
  gemm_k<<<gGemm, 128, 0, stream>>>(A, W0, B, N);
  aggregate_k<<<gAgg, blk, 0, stream>>>(offs, srow, snorm, B, dinv, b0,
                                        bng, bnb, bnm, bnv, 1, A, N);
  // layer 1
  gemm_k<<<gGemm, 128, 0, stream>>>(A, W1, B, N);
  aggregate_k<<<gAgg, blk, 0, stream>>>(offs, srow, snorm, B, dinv, b1,
                                        bng, bnb, bnm, bnv, 1, A, N);
  // layer 2 (no bn/relu)
  gemm_k<<<gGemm, 128, 0, stream>>>(A, W2, B, N);
  aggregate_k<<<gAgg, blk, 0, stream>>>(offs, srow, snorm, B, dinv, b2,
                                        bng, bnb, bnm, bnv, 0, A, N);

  start_k<<<1, 128, 0, stream>>>(b32, strt, N);
  dim3 pgrid(16, GD);
  pool1_k<<<pgrid, 128, 0, stream>>>(A, strt, sums);
  mlp_k<<<GD, 128, 0, stream>>>(sums, strt, mW1, mb1, mW2, mb2, out);
}

// Round 7
// 407.144 us; speedup vs baseline: 11.0359x; 1.3732x over previous
//
#include <hip/hip_runtime.h>
#include <hip/hip_bf16.h>
#include <stdint.h>

#define HD 128
#define GD 64
#define OUTD 16

typedef unsigned short u16;
typedef __attribute__((ext_vector_type(8))) short short8;
typedef __attribute__((ext_vector_type(4))) float f32x4;

__device__ __forceinline__ float bf2f(u16 u) {
  union { uint32_t i; float f; } v; v.i = ((uint32_t)u) << 16; return v.f;
}
__device__ __forceinline__ u16 f2bf(float f) {
  union { __hip_bfloat16 h; u16 u; } v; v.h = __float2bfloat16(f); return v.u;
}

// ---------------------------------------------------------------- utilities
__global__ void zero_f_k(float* p, int n) {
  int i = blockIdx.x * 256 + threadIdx.x;
  if (i < n) p[i] = 0.f;
}
__global__ void zero_i_k(int* p, int n) {
  int i = blockIdx.x * 256 + threadIdx.x;
  if (i < n) p[i] = 0;
}

// Detect int64 vs int32 layout of edge_index.
__global__ void detect_k(const int* ei, int* flag) {
  if (threadIdx.x == 0 && blockIdx.x == 0) {
    int all0 = 1;
    for (int k = 1; k < 128; k += 2) all0 &= (ei[k] == 0);
    *flag = all0;
  }
}

// Normalize edge_index and batch to int32 in ws.
__global__ void convert_idx_k(const int* ei, const int* bt, int* idx, int* b32,
                              int E, int N, const int* flag) {
  int i = blockIdx.x * 256 + threadIdx.x;
  int is64 = *flag;
  if (i < 2 * E) {
    int v = is64 ? ei[2 * i] : ei[i];
    idx[i] = (v < 0) ? 0 : (v >= N ? N - 1 : v);
  }
  if (i < N) {
    int v = is64 ? bt[2 * i] : bt[i];
    b32[i] = (v < 0) ? 0 : (v >= GD ? GD - 1 : v);
  }
}

// privatized in-degree count: replica k = blockIdx & 7
__global__ void count_k(const int* __restrict__ idx, int* __restrict__ cnt8,
                        int E, int N) {
  int e = blockIdx.x * 256 + threadIdx.x;
  if (e >= E) return;
  int k = blockIdx.x & 7;
  int col = idx[E + e];
  atomicAdd(&cnt8[k * N + col], 1);
}

__global__ void reduce_cnt_k(const int* __restrict__ cnt8, int* __restrict__ cnt, int N) {
  int n = blockIdx.x * 256 + threadIdx.x;
  if (n >= N) return;
  int s = 0;
#pragma unroll
  for (int k = 0; k < 8; ++k) s += cnt8[k * N + n];
  cnt[n] = s;
}

// ---- 3-step exclusive scan of cnt[0..N) -> offs
__global__ void scan1_k(const int* __restrict__ cnt, int* __restrict__ offs,
                        int* __restrict__ bsum, int Np) {
  __shared__ int s[1024];
  int i = blockIdx.x * 1024 + threadIdx.x;
  int v = (i < Np) ? cnt[i] : 0;
  s[threadIdx.x] = v;
  __syncthreads();
  for (int off = 1; off < 1024; off <<= 1) {
    int t = (threadIdx.x >= off) ? s[threadIdx.x - off] : 0;
    __syncthreads();
    s[threadIdx.x] += t;
    __syncthreads();
  }
  if (i < Np) offs[i] = s[threadIdx.x] - v;
  if (threadIdx.x == 1023) bsum[blockIdx.x] = s[1023];
}
__global__ void scan2_k(int* bsum, int nb) {
  if (threadIdx.x == 0 && blockIdx.x == 0) {
    int sum = 0;
    for (int i = 0; i < nb; ++i) { int v = bsum[i]; bsum[i] = sum; sum += v; }
  }
}
__global__ void scan3_k(int* __restrict__ offs, const int* __restrict__ bsum,
                        int Np, int E) {
  int i = blockIdx.x * 256 + threadIdx.x;
  if (i < Np) offs[i] = offs[i] + bsum[i >> 10];
  if (i == 0) offs[Np] = E;
}

// per-replica cursors
__global__ void curs8_k(const int* __restrict__ offs, const int* __restrict__ cnt8,
                        int* __restrict__ curs8, int N) {
  int n = blockIdx.x * 256 + threadIdx.x;
  if (n >= N) return;
  int run = offs[n];
#pragma unroll
  for (int k = 0; k < 8; ++k) { curs8[k * N + n] = run; run += cnt8[k * N + n]; }
}

// fill CSC (sorted by destination col): srow + sorted |w|
__global__ void fill_k(const int* __restrict__ idx, const float* __restrict__ ea,
                       int* __restrict__ curs8, int* __restrict__ srow,
                       float* __restrict__ sws, int E, int N) {
  int e = blockIdx.x * 256 + threadIdx.x;
  if (e >= E) return;
  int k = blockIdx.x & 7;
  int row = idx[e], col = idx[E + e];
  float a = ea[e];
  float w = isnan(a) ? 0.f : fabsf(a);
  int p = atomicAdd(&curs8[k * N + col], 1);
  srow[p] = row;
  sws[p] = w;
}

// dinv[n] = rsqrt(sum of in-weights + 1)
__global__ void deg_k(const int* __restrict__ offs, const float* __restrict__ sws,
                      float* __restrict__ dinv, int N) {
  int n = blockIdx.x * 256 + threadIdx.x;
  if (n >= N) return;
  int p = offs[n], pe = offs[n + 1];
  float s = 0.f;
  for (; p < pe; ++p) s += sws[p];
  dinv[n] = rsqrtf(s + 1.0f);
}

// snorm[p] = dinv[row]*w*dinv[col]
__global__ void normcsc_k(const int* __restrict__ offs, const int* __restrict__ srow,
                          const float* __restrict__ sws, const float* __restrict__ dinv,
                          float* __restrict__ snorm, int N) {
  int n = blockIdx.x * 256 + threadIdx.x;
  if (n >= N) return;
  float dc = dinv[n];
  int p = offs[n], pe = offs[n + 1];
  for (; p < pe; ++p) snorm[p] = dinv[srow[p]] * sws[p] * dc;
}

// h0 = concat(nan_to_num(x), isnan(x))  [N,128] bf16
__global__ void build_h0_k(const float* __restrict__ x, u16* __restrict__ A, int N) {
  int i = blockIdx.x * 256 + threadIdx.x;
  if (i >= N * HD) return;
  int n = i >> 7, f = i & 127;
  float v;
  if (f < 64) { float u = x[n * 64 + f];      v = isnan(u) ? 0.f : u; }
  else        { float u = x[n * 64 + f - 64]; v = isnan(u) ? 1.f : 0.f; }
  A[i] = f2bf(v);
}

// transpose+convert weights: Wt[n][k] = bf16(W[k][n])   (128x128)
__global__ void convw_k(const float* __restrict__ W, u16* __restrict__ Wt) {
  int i = blockIdx.x * 256 + threadIdx.x;
  if (i >= HD * HD) return;
  int n = i >> 7, k = i & 127;
  Wt[i] = f2bf(W[k * HD + n]);
}

// B[N,128] = A[N,128] @ W[128,128]  via MFMA 16x16x32 bf16, fp32 accum.
// block = 256 (4 waves), 64 rows/block; Wt staged in LDS (pad stride 136 shorts).
__global__ __launch_bounds__(256)
void gemm_k(const u16* __restrict__ A, const u16* __restrict__ Wt,
            u16* __restrict__ B, int N) {
  __shared__ u16 sw[128 * 136];
  const int t = threadIdx.x;
  {
    const uint32_t* src = (const uint32_t*)Wt;
    uint32_t* dst = (uint32_t*)sw;
#pragma unroll
    for (int k = 0; k < 32; ++k) {
      int q = t + k * 256;        // 0..8191 uints
      int r = q >> 6;             // row 0..127
      int u = q & 63;
      dst[r * 68 + u] = src[r * 64 + u];
    }
  }
  __syncthreads();
  const int w = t >> 6;           // wave 0..3
  const int lane = t & 63;
  const int m = lane & 15;
  const int qd = lane >> 4;       // 0..3
  const int arow = blockIdx.x * 64 + w * 16 + m;
  short8 afr[4];
  if (arow < N) {
    const short8* ap = (const short8*)(A + (size_t)arow * HD);
#pragma unroll
    for (int s = 0; s < 4; ++s) afr[s] = ap[4 * s + qd];  // k = 32s+8qd..+7
  } else {
    short8 z = {0, 0, 0, 0, 0, 0, 0, 0};
#pragma unroll
    for (int s = 0; s < 4; ++s) afr[s] = z;
  }
  const int orow = blockIdx.x * 64 + w * 16 + qd * 4;
#pragma unroll
  for (int c = 0; c < 8; ++c) {
    f32x4 acc = {0.f, 0.f, 0.f, 0.f};
    const int n = c * 16 + m;
#pragma unroll
    for (int s = 0; s < 4; ++s) {
      short8 bfr = *(const short8*)(sw + n * 136 + 32 * s + 8 * qd);
      acc = __builtin_amdgcn_mfma_f32_16x16x32_bf16(afr[s], bfr, acc, 0, 0, 0);
    }
#pragma unroll
    for (int r = 0; r < 4; ++r) {
      int rr = orow + r;
      if (rr < N) B[(size_t)rr * HD + n] = f2bf(acc[r]);
    }
  }
}

// Fused: A[n] = BN?ReLU( dinv[n]^2*B[n] + bias + sum_in norm*B[row] )
// bf16 gather, fp32 accumulate, bf16 store. 32 lanes/node.
__global__ __launch_bounds__(256)
void aggregate_k(const int* __restrict__ offs, const int* __restrict__ srow,
                 const float* __restrict__ snorm, const u16* __restrict__ B,
                 const float* __restrict__ dinv, const float* __restrict__ bias,
                 const float* __restrict__ gamma, const float* __restrict__ beta,
                 const float* __restrict__ mean, const float* __restrict__ var,
                 int do_bn, u16* __restrict__ A, int N) {
  int tid = blockIdx.x * 256 + threadIdx.x;
  int n = tid >> 5;
  if (n >= N) return;
  int f4 = (tid & 31) << 2;
  float d = dinv[n];
  ushort4 bu = *(const ushort4*)(B + (size_t)n * HD + f4);
  float ax = d * d * bf2f(bu.x) + bias[f4 + 0];
  float ay = d * d * bf2f(bu.y) + bias[f4 + 1];
  float az = d * d * bf2f(bu.z) + bias[f4 + 2];
  float aw = d * d * bf2f(bu.w) + bias[f4 + 3];

  int p = offs[n], pe = offs[n + 1];
  for (; p + 1 < pe; p += 2) {
    int r0 = srow[p], r1 = srow[p + 1];
    float w0 = snorm[p], w1 = snorm[p + 1];
    ushort4 h0 = *(const ushort4*)(B + (size_t)r0 * HD + f4);
    ushort4 h1 = *(const ushort4*)(B + (size_t)r1 * HD + f4);
    ax += w0 * bf2f(h0.x) + w1 * bf2f(h1.x);
    ay += w0 * bf2f(h0.y) + w1 * bf2f(h1.y);
    az += w0 * bf2f(h0.z) + w1 * bf2f(h1.z);
    aw += w0 * bf2f(h0.w) + w1 * bf2f(h1.w);
  }
  if (p < pe) {
    int r0 = srow[p];
    float w0 = snorm[p];
    ushort4 h0 = *(const ushort4*)(B + (size_t)r0 * HD + f4);
    ax += w0 * bf2f(h0.x); ay += w0 * bf2f(h0.y);
    az += w0 * bf2f(h0.z); aw += w0 * bf2f(h0.w);
  }
  if (do_bn) {
    float s0 = gamma[f4 + 0] * rsqrtf(var[f4 + 0] + 1e-5f);
    float s1 = gamma[f4 + 1] * rsqrtf(var[f4 + 1] + 1e-5f);
    float s2 = gamma[f4 + 2] * rsqrtf(var[f4 + 2] + 1e-5f);
    float s3 = gamma[f4 + 3] * rsqrtf(var[f4 + 3] + 1e-5f);
    ax = (ax - mean[f4 + 0]) * s0 + beta[f4 + 0];
    ay = (ay - mean[f4 + 1]) * s1 + beta[f4 + 1];
    az = (az - mean[f4 + 2]) * s2 + beta[f4 + 2];
    aw = (aw - mean[f4 + 3]) * s3 + beta[f4 + 3];
    ax = ax > 0.f ? ax : 0.f;
    ay = ay > 0.f ? ay : 0.f;
    az = az > 0.f ? az : 0.f;
    aw = aw > 0.f ? aw : 0.f;
  }
  ushort4 o;
  o.x = f2bf(ax); o.y = f2bf(ay); o.z = f2bf(az); o.w = f2bf(aw);
  *(ushort4*)(A + (size_t)n * HD + f4) = o;
}

// segment starts via binary search on sorted batch
__global__ void start_k(const int* __restrict__ b32, int* __restrict__ start, int N) {
  int b = threadIdx.x;
  if (b > GD) return;
  int lo = 0, hi = N;
  while (lo < hi) {
    int mid = (lo + hi) >> 1;
    if (b32[mid] < b) lo = mid + 1; else hi = mid;
  }
  start[b] = lo;
}

// two-stage mean pool, stage 1 (bf16 input)
__global__ __launch_bounds__(128)
void pool1_k(const u16* __restrict__ A, const int* __restrict__ start,
             float* __restrict__ sums) {
  int b = blockIdx.y;
  int s = start[b], e = start[b + 1];
  int len = e - s;
  if (len <= 0) return;
  int nch = gridDim.x;
  int ch = (len + nch - 1) / nch;
  int lo = s + blockIdx.x * ch;
  int hi = lo + ch; if (hi > e) hi = e;
  if (lo >= hi) return;
  int j = threadIdx.x;
  float a0 = 0.f, a1 = 0.f, a2 = 0.f, a3 = 0.f;
  int n = lo;
  for (; n + 3 < hi; n += 4) {
    a0 += bf2f(A[(size_t)(n + 0) * HD + j]);
    a1 += bf2f(A[(size_t)(n + 1) * HD + j]);
    a2 += bf2f(A[(size_t)(n + 2) * HD + j]);
    a3 += bf2f(A[(size_t)(n + 3) * HD + j]);
  }
  for (; n < hi; ++n) a0 += bf2f(A[(size_t)n * HD + j]);
  unsafeAtomicAdd(&sums[b * HD + j], (a0 + a1) + (a2 + a3));
}

// out = gelu((sums/cnt)@mW1+mb1) @ mW2 + mb2
__global__ __launch_bounds__(128)
void mlp_k(const float* __restrict__ sums, const int* __restrict__ start,
           const float* __restrict__ mW1, const float* __restrict__ mb1,
           const float* __restrict__ mW2, const float* __restrict__ mb2,
           float* __restrict__ out) {
  __shared__ float sg[128];
  __shared__ float st[128];
  int b = blockIdx.x, j = threadIdx.x;
  int cnt = start[b + 1] - start[b];
  float inv = 1.0f / (float)(cnt > 0 ? cnt : 1);
  sg[j] = sums[b * HD + j] * inv;
  __syncthreads();
  float s = mb1[j];
#pragma unroll 4
  for (int i = 0; i < 128; ++i) s += sg[i] * mW1[i * 128 + j];
  float ge = 0.5f * s * (1.0f + erff(s * 0.70710678118654752f));
  st[j] = ge;
  __syncthreads();
  if (j < OUTD) {
    float o = mb2[j];
#pragma unroll 4
    for (int k = 0; k < 128; ++k) o += st[k] * mW2[k * OUTD + j];
    out[b * OUTD + j] = o;
  }
}

// ---------------------------------------------------------------- launch
extern "C" void kernel_launch(void* const* d_in, const int* in_sizes, int n_in,
                              void* d_out, int out_size, void* d_ws, size_t ws_size,
                              hipStream_t stream) {
  const float* x   = (const float*)d_in[0];
  const int* ei    = (const int*)d_in[1];
  const float* ea  = (const float*)d_in[2];
  const int* bt    = (const int*)d_in[3];
  const float* W0  = (const float*)d_in[4];
  const float* b0  = (const float*)d_in[5];
  const float* W1  = (const float*)d_in[6];
  const float* b1  = (const float*)d_in[7];
  const float* W2  = (const float*)d_in[8];
  const float* b2  = (const float*)d_in[9];
  const float* bng = (const float*)d_in[10];
  const float* bnb = (const float*)d_in[11];
  const float* bnm = (const float*)d_in[12];
  const float* bnv = (const float*)d_in[13];
  const float* mW1 = (const float*)d_in[14];
  const float* mb1 = (const float*)d_in[15];
  const float* mW2 = (const float*)d_in[16];
  const float* mb2 = (const float*)d_in[17];
  float* out = (float*)d_out;

  const int N = in_sizes[0] / 64;      // 50000
  const int E = in_sizes[2];           // 800000

  char* ws = (char*)d_ws;
  size_t NB2 = (size_t)N * HD * 2;     // bf16 feature buffer
  u16* A       = (u16*)(ws);
  u16* B       = (u16*)(ws + NB2);
  char* q      = ws + 2 * NB2;
  u16* Wt0     = (u16*)q;              q += (size_t)HD * HD * 2;
  u16* Wt1     = (u16*)q;              q += (size_t)HD * HD * 2;
  u16* Wt2     = (u16*)q;              q += (size_t)HD * HD * 2;
  float* snorm = (float*)q;            q += (size_t)E * 4;
  int*   srow  = (int*)q;              q += (size_t)E * 4;
  float* sws   = (float*)q;            q += (size_t)E * 4;
  int*   idx   = (int*)q;              q += (size_t)2 * E * 4;
  float* dinv  = (float*)q;            q += (size_t)N * 4;
  int*   cnt8  = (int*)q;              q += (size_t)8 * N * 4;
  int*   curs8 = (int*)q;              q += (size_t)8 * N * 4;
  int*   cnt   = (int*)q;              q += (size_t)N * 4;
  int*   offs  = (int*)q;              q += (size_t)(N + 2) * 4;
  int*   b32   = (int*)q;              q += (size_t)N * 4;
  int*   bsum  = (int*)q;              q += 64 * 4;
  float* sums  = (float*)q;            q += GD * HD * 4;
  int*   strt  = (int*)q;              q += 68 * 4;
  int*   flag  = (int*)q;

  const int NH = N * HD;
  dim3 blk(256);
  int gNH = (NH + 255) / 256;
  int gE  = (E + 255) / 256;
  int gN  = (N + 255) / 256;
  int gCv = (2 * E + 255) / 256;
  int gW  = (HD * HD + 255) / 256;
  int nb1024 = (N + 1023) / 1024;

  detect_k<<<1, 64, 0, stream>>>(ei, flag);
  convert_idx_k<<<gCv, blk, 0, stream>>>(ei, bt, idx, b32, E, N, flag);
  zero_i_k<<<(8 * N + 255) / 256, blk, 0, stream>>>(cnt8, 8 * N);
  zero_f_k<<<(GD * HD + 255) / 256, blk, 0, stream>>>(sums, GD * HD);
  convw_k<<<gW, blk, 0, stream>>>(W0, Wt0);
  convw_k<<<gW, blk, 0, stream>>>(W1, Wt1);
  convw_k<<<gW, blk, 0, stream>>>(W2, Wt2);
  count_k<<<gE, blk, 0, stream>>>(idx, cnt8, E, N);
  reduce_cnt_k<<<gN, blk, 0, stream>>>(cnt8, cnt, N);
  scan1_k<<<nb1024, 1024, 0, stream>>>(cnt, offs, bsum, N);
  scan2_k<<<1, 64, 0, stream>>>(bsum, nb1024);
  scan3_k<<<gN, blk, 0, stream>>>(offs, bsum, N, E);
  curs8_k<<<gN, blk, 0, stream>>>(offs, cnt8, curs8, N);
  fill_k<<<gE, blk, 0, stream>>>(idx, ea, curs8, srow, sws, E, N);
  deg_k<<<gN, blk, 0, stream>>>(offs, sws, dinv, N);
  normcsc_k<<<gN, blk, 0, stream>>>(offs, srow, sws, dinv, snorm, N);
  build_h0_k<<<gNH, blk, 0, stream>>>(x, A, N);

  int gGemm = (N + 63) / 64;
  int gAgg  = (N * 32 + 255) / 256;

  // layer 0
  gemm_k<<<gGemm, 256, 0, stream>>>(A, Wt0, B, N);
  aggregate_k<<<gAgg, blk, 0, stream>>>(offs, srow, snorm, B, dinv, b0,
                                        bng, bnb, bnm, bnv, 1, A, N);
  // layer 1
  gemm_k<<<gGemm, 256, 0, stream>>>(A, Wt1, B, N);
  aggregate_k<<<gAgg, blk, 0, stream>>>(offs, srow, snorm, B, dinv, b1,
                                        bng, bnb, bnm, bnv, 1, A, N);
  // layer 2 (no bn/relu)
  gemm_k<<<gGemm, 256, 0, stream>>>(A, Wt2, B, N);
  aggregate_k<<<gAgg, blk, 0, stream>>>(offs, srow, snorm, B, dinv, b2,
                                        bng, bnb, bnm, bnv, 0, A, N);

  start_k<<<1, 128, 0, stream>>>(b32, strt, N);
  dim3 pgrid(16, GD);
  pool1_k<<<pgrid, 128, 0, stream>>>(A, strt, sums);
  mlp_k<<<GD, 128, 0, stream>>>(sums, strt, mW1, mb1, mW2, mb2, out);
}